// Round 1
// 223.318 us; speedup vs baseline: 1.0209x; 1.0209x over previous
//
#include <hip/hip_runtime.h>

// reconstruction_loss: charbonnier_mean(get_msfa(X,4), get_msfa(Y,4))
// X, Y: [B=8, C=16, H=512, W=512] fp32. Pixel (b,h,w) gathers channel
// c = (h%4)*4 + (w%4). Loss = mean over B*H*W of sqrt(d^2 + 1e-6).
//
// Access-shape inversion: instead of one thread per PIXEL (scattered dword
// gather across 4 channel planes), iterate over the USED ROWS. Channel c
// only contributes rows h with h%4 == c>>2; within such a row exactly one
// element of each float4 is used (j = c&3, wave-uniform). So we stream the
// needed quarter of each tensor with fully-coalesced float4 loads
// (consecutive lanes -> contiguous 1 KiB per wave-instruction) and select
// the used element in-register. HBM bytes unchanged (64 MiB floor from
// 64B line granularity), but traffic is now pure streaming, not gather.

#define EPS_F 1e-6f

constexpr int kBlocks  = 1024;
constexpr int kThreads = 256;
constexpr int kNPix    = 8 * 512 * 512;                 // 2097152 pixels
constexpr int kNVec    = kNPix;                         // one float4-pair per pixel
constexpr int kPerThr  = kNVec / (kBlocks * kThreads);  // 8

__global__ __launch_bounds__(kThreads) void msfa_charb_partial(
    const float4* __restrict__ X, const float4* __restrict__ Y,
    float* __restrict__ partial)
{
    const int tid      = blockIdx.x * kThreads + threadIdx.x;
    const int nthreads = kBlocks * kThreads;            // 262144

    float acc = 0.0f;
#pragma unroll
    for (int it = 0; it < kPerThr; ++it) {
        // v enumerates (b, c, used_row r, float4 q); consecutive lanes ->
        // consecutive q -> contiguous addresses within one row.
        const int v   = tid + it * nthreads;
        const int q   = v & 127;          // float4 index within row (128/row)
        const int row = v >> 7;           // global used-row id [0, 16384)
        const int r   = row & 127;        // used-row index within channel
        const int c   = (row >> 7) & 15;  // channel
        const int b   = row >> 11;        // batch
        const int h   = (r << 2) | (c >> 2);            // actual image row
        const int j   = c & 3;            // used element within float4 (== w%4)
        const int o4  = (((b << 4) + c) << 16) + (h << 7) + q; // float4 offset

        const float4 x = X[o4];
        const float4 y = Y[o4];
        // j is wave-uniform (a wave spans 64 consecutive q in one row);
        // 3-deep cndmask select, no divergence.
        const float xe = (j & 2) ? ((j & 1) ? x.w : x.z) : ((j & 1) ? x.y : x.x);
        const float ye = (j & 2) ? ((j & 1) ? y.w : y.z) : ((j & 1) ? y.y : y.x);
        const float d  = xe - ye;
        acc += sqrtf(fmaf(d, d, EPS_F));
    }

    // wave64 butterfly reduce
#pragma unroll
    for (int s = 32; s > 0; s >>= 1)
        acc += __shfl_down(acc, s, 64);

    __shared__ float sdata[kThreads / 64];
    const int lane = threadIdx.x & 63;
    const int wave = threadIdx.x >> 6;
    if (lane == 0) sdata[wave] = acc;
    __syncthreads();
    if (threadIdx.x == 0) {
        float t = 0.0f;
#pragma unroll
        for (int i = 0; i < kThreads / 64; ++i) t += sdata[i];
        partial[blockIdx.x] = t;
    }
}

__global__ __launch_bounds__(1024) void msfa_finalize(
    const float* __restrict__ partial, float* __restrict__ out)
{
    float v = partial[threadIdx.x];                     // 1024 partials
#pragma unroll
    for (int s = 32; s > 0; s >>= 1)
        v += __shfl_down(v, s, 64);

    __shared__ float sdata[16];
    const int lane = threadIdx.x & 63;
    const int wave = threadIdx.x >> 6;
    if (lane == 0) sdata[wave] = v;
    __syncthreads();
    if (threadIdx.x == 0) {
        float t = 0.0f;
#pragma unroll
        for (int i = 0; i < 16; ++i) t += sdata[i];
        out[0] = t * (1.0f / (float)kNPix);
    }
}

extern "C" void kernel_launch(void* const* d_in, const int* in_sizes, int n_in,
                              void* d_out, int out_size, void* d_ws, size_t ws_size,
                              hipStream_t stream)
{
    const float4* X = (const float4*)d_in[0];
    const float4* Y = (const float4*)d_in[1];
    float* partial  = (float*)d_ws;                     // 4 KiB scratch
    float* out      = (float*)d_out;

    msfa_charb_partial<<<kBlocks, kThreads, 0, stream>>>(X, Y, partial);
    msfa_finalize<<<1, 1024, 0, stream>>>(partial, out);
}

// Round 2
// 222.975 us; speedup vs baseline: 1.0225x; 1.0015x over previous
//
#include <hip/hip_runtime.h>

// reconstruction_loss: charbonnier_mean(get_msfa(X,4), get_msfa(Y,4))
// X, Y: [B=8, C=16, H=512, W=512] fp32. Pixel (b,h,w) gathers channel
// c = (h%4)*4 + (w%4). Loss = mean over B*H*W of sqrt(d^2 + 1e-6).
//
// Used-row streaming: channel c only contributes rows h with h%4 == c>>2;
// within such a row exactly one element of each float4 is used (j = c&3,
// wave-uniform). We stream that quarter of each tensor fully coalesced.
// HBM floor: needed 16 MiB/tensor, fetched 64 MiB total (64B-line
// granularity, each line 1/4-utilized, touched exactly once) ~= 10-13 us.
//
// This revision: per-thread (q,r,c) are loop-invariant; the 8 iterations
// only step the batch (constant 16 MiB address stride). All 16 float4
// loads (8 X + 8 Y) issue back-to-back before any use -> 256 B in flight
// per thread, maximum MLP. Loads are nontemporal (read-once stream larger
// than L2).

#define EPS_F 1e-6f

typedef float f32x4 __attribute__((ext_vector_type(4)));

constexpr int kBlocks  = 1024;
constexpr int kThreads = 256;
constexpr int kNPix    = 8 * 512 * 512;     // 2097152 pixels
constexpr int kBatches = 8;

__global__ __launch_bounds__(kThreads) void msfa_charb_partial(
    const f32x4* __restrict__ X, const f32x4* __restrict__ Y,
    float* __restrict__ partial)
{
    const int tid = blockIdx.x * kThreads + threadIdx.x;   // [0, 262144)

    // tid -> (q, r, c): loop-invariant. One (c, r) used-row covers 128
    // float4s; 2048 used rows per batch; batch is the per-thread loop.
    const int q   = tid & 127;            // float4 index within row
    const int row = tid >> 7;             // [0, 2048) = (c, r)
    const int r   = row & 127;            // used-row index within channel
    const int c   = (row >> 7) & 15;      // channel
    const int h   = (r << 2) | (c >> 2);  // actual image row (h%4 == c>>2)
    const int j   = c & 3;                // used lane of the float4 (== w%4)
    const int base = (c << 16) + (h << 7) + q;   // float4 offset, batch 0
    // batch stride = C*H*W/4 float4 = 1<<20 (16 MiB)

    f32x4 xs[kBatches], ys[kBatches];
#pragma unroll
    for (int b = 0; b < kBatches; ++b) {
        const int o = base + (b << 20);
        xs[b] = __builtin_nontemporal_load(X + o);
        ys[b] = __builtin_nontemporal_load(Y + o);
    }

    float acc = 0.0f;
#pragma unroll
    for (int b = 0; b < kBatches; ++b) {
        const float xe = (j & 2) ? ((j & 1) ? xs[b].w : xs[b].z)
                                 : ((j & 1) ? xs[b].y : xs[b].x);
        const float ye = (j & 2) ? ((j & 1) ? ys[b].w : ys[b].z)
                                 : ((j & 1) ? ys[b].y : ys[b].x);
        const float d  = xe - ye;
        acc += sqrtf(fmaf(d, d, EPS_F));
    }

    // wave64 butterfly reduce
#pragma unroll
    for (int s = 32; s > 0; s >>= 1)
        acc += __shfl_down(acc, s, 64);

    __shared__ float sdata[kThreads / 64];
    const int lane = threadIdx.x & 63;
    const int wave = threadIdx.x >> 6;
    if (lane == 0) sdata[wave] = acc;
    __syncthreads();
    if (threadIdx.x == 0) {
        float t = 0.0f;
#pragma unroll
        for (int i = 0; i < kThreads / 64; ++i) t += sdata[i];
        partial[blockIdx.x] = t;
    }
}

__global__ __launch_bounds__(1024) void msfa_finalize(
    const float* __restrict__ partial, float* __restrict__ out)
{
    float v = partial[threadIdx.x];                        // 1024 partials
#pragma unroll
    for (int s = 32; s > 0; s >>= 1)
        v += __shfl_down(v, s, 64);

    __shared__ float sdata[16];
    const int lane = threadIdx.x & 63;
    const int wave = threadIdx.x >> 6;
    if (lane == 0) sdata[wave] = v;
    __syncthreads();
    if (threadIdx.x == 0) {
        float t = 0.0f;
#pragma unroll
        for (int i = 0; i < 16; ++i) t += sdata[i];
        out[0] = t * (1.0f / (float)kNPix);
    }
}

extern "C" void kernel_launch(void* const* d_in, const int* in_sizes, int n_in,
                              void* d_out, int out_size, void* d_ws, size_t ws_size,
                              hipStream_t stream)
{
    const f32x4* X = (const f32x4*)d_in[0];
    const f32x4* Y = (const f32x4*)d_in[1];
    float* partial = (float*)d_ws;                         // 4 KiB scratch
    float* out     = (float*)d_out;

    msfa_charb_partial<<<kBlocks, kThreads, 0, stream>>>(X, Y, partial);
    msfa_finalize<<<1, 1024, 0, stream>>>(partial, out);
}